// Round 5
// baseline (420.306 us; speedup 1.0000x reference)
//
#include <hip/hip_runtime.h>
#include <hip/hip_bf16.h>
#include <stdint.h>
#include <stddef.h>

#define SEQ  8192
#define DIN  1024
#define DOUT 1024
#define NB   512   // grid: exactly 2 blocks/CU on 256 CUs (64 KB LDS, <=256 VGPR)

typedef __hip_bfloat16 bf16;
typedef short bf16x8 __attribute__((ext_vector_type(8)));   // 8 bf16 = 4 VGPRs
typedef float f32x4  __attribute__((ext_vector_type(4)));

// async global->LDS, 16B per lane; dest = wave-uniform base + lane*16
#define GLOAD_LDS16(gptr, lptr)                                                     \
  __builtin_amdgcn_global_load_lds(                                                 \
      (const __attribute__((address_space(1))) void*)(gptr),                        \
      (__attribute__((address_space(3))) void*)(lptr), 16, 0, 0)

__device__ inline void store_out(float* p, float v) { *p = v; }
__device__ inline void store_out(bf16* p, float v) { *p = __float2bfloat16(v); }
__device__ inline short bfbits(float f) { bf16 b = __float2bfloat16(f); return *(short*)&b; }
__device__ inline float bf2f(short u) {
  unsigned v = ((unsigned)(unsigned short)u) << 16;
  return __uint_as_float(v);
}

// device-scope grid barrier: fire-and-forget atomic arrival + coherent-load spin.
// ctr must be zeroed before launch (hipMemsetAsync). Co-residency is guaranteed
// by exact-fit occupancy (512 blocks, 2/CU). Poll bound avoids a hard hang.
__device__ __forceinline__ void grid_barrier(unsigned* c, unsigned target) {
  __syncthreads();
  if (threadIdx.x == 0) {
    __threadfence();                 // release: prior stores visible device-wide
    atomicAdd(c, 1u);                // device-scope, non-returning -> pipelined
    int polls = 0;
    while (__hip_atomic_load(c, __ATOMIC_RELAXED, __HIP_MEMORY_SCOPE_AGENT) < target) {
      __builtin_amdgcn_s_sleep(2);
      if (++polls > (1 << 26)) break;  // failsafe: terminate rather than hang
    }
    __threadfence();                 // acquire
  }
  __syncthreads();
}

// ---------------------------------------------------------------------------
// 128x128 tile, BK=64, XOR-swizzled LDS, double-buffered (vmcnt(8) late wait).
// As/Bs: 2 buffers x 128*64 bf16 each -> 64 KB total.
template <typename OutT>
__device__ __forceinline__ void gemm128_body(
    const bf16* __restrict__ A, const bf16* __restrict__ B, OutT* __restrict__ C,
    int bx, int by, int K, int lda, int ldb, int ldc, bf16* As, bf16* Bs)
{
  const int lane = threadIdx.x & 63;
  const int wave = threadIdx.x >> 6;
  const int m0 = by * 128, n0 = bx * 128;

  const int sR = lane >> 3;
  const int sC = (lane & 7) ^ sR;       // XOR swizzle -> conflict-free b128 reads
  const bf16* gA = A + (size_t)(m0 + sR) * lda + sC * 8;
  const bf16* gB = B + (size_t)(n0 + sR) * ldb + sC * 8;

  f32x4 acc[4][4];
#pragma unroll
  for (int i = 0; i < 4; ++i)
#pragma unroll
    for (int j = 0; j < 4; ++j)
      acc[i][j] = (f32x4){0.f, 0.f, 0.f, 0.f};

  const int wr = wave >> 1, wc = wave & 1;
  const int mW = wr * 64, nW = wc * 64;
  const int fragRow = lane & 15;
  const int quad = lane >> 4;

  auto stage = [&](int kt, int buf) {
    bf16* dA = As + buf * (128 * 64);
    bf16* dB = Bs + buf * (128 * 64);
#pragma unroll
    for (int t = 0; t < 4; ++t) {
      const int R = (t * 4 + wave) * 8;
      GLOAD_LDS16(gA + (size_t)R * lda + kt, &dA[R * 64]);
      GLOAD_LDS16(gB + (size_t)R * ldb + kt, &dB[R * 64]);
    }
  };

  const int nT = K >> 6;
  stage(0, 0);
  for (int kt = 0; kt < nT; ++kt) {
    const int buf = kt & 1;
    if (kt + 1 < nT) {
      stage((kt + 1) << 6, buf ^ 1);
      asm volatile("s_waitcnt vmcnt(8)" ::: "memory");   // tile kt complete
    } else {
      asm volatile("s_waitcnt vmcnt(0)" ::: "memory");
    }
    asm volatile("s_barrier" ::: "memory");

    const bf16* Ab = As + buf * (128 * 64);
    const bf16* Bb = Bs + buf * (128 * 64);
    bf16x8 afr[2][4], bfr[2][4];
#pragma unroll
    for (int s = 0; s < 2; ++s) {
      const int cw = s * 4 + quad;
#pragma unroll
      for (int i = 0; i < 4; ++i) {
        const int ra = mW + i * 16 + fragRow;
        afr[s][i] = *(const bf16x8*)&Ab[ra * 64 + ((cw ^ (ra & 7)) << 3)];
        const int rb = nW + i * 16 + fragRow;
        bfr[s][i] = *(const bf16x8*)&Bb[rb * 64 + ((cw ^ (rb & 7)) << 3)];
      }
    }
    asm volatile("s_waitcnt lgkmcnt(0)" ::: "memory");
    asm volatile("s_barrier" ::: "memory");

#pragma unroll
    for (int s = 0; s < 2; ++s)
#pragma unroll
      for (int i = 0; i < 4; ++i)
#pragma unroll
        for (int j = 0; j < 4; ++j)
          acc[i][j] = __builtin_amdgcn_mfma_f32_16x16x32_bf16(afr[s][i], bfr[s][j], acc[i][j], 0, 0, 0);
  }

  const int cCol  = lane & 15;
  const int cRow4 = quad * 4;
#pragma unroll
  for (int i = 0; i < 4; ++i)
#pragma unroll
    for (int j = 0; j < 4; ++j) {
      const int row = m0 + mW + i * 16 + cRow4;
      const int col = n0 + nW + j * 16 + cCol;
#pragma unroll
      for (int r = 0; r < 4; ++r)
        store_out(&C[(size_t)(row + r) * ldc + col], acc[i][j][r]);
    }
}

// 64x64 tile, BK=64, XOR swizzle, TRIPLE-buffered (prefetch depth 2 to cover
// ~900cyc load latency in short 16-iter K-loops). As/Bs: 3 x 64*64 bf16 = 48 KB.
template <typename OutT>
__device__ __forceinline__ void gemm64_body(
    const bf16* __restrict__ A, const bf16* __restrict__ B, OutT* __restrict__ C,
    int bx, int by, int K, int lda, int ldb, int ldc, bf16* As, bf16* Bs)
{
  const int lane = threadIdx.x & 63;
  const int wave = threadIdx.x >> 6;
  const int m0 = by * 64, n0 = bx * 64;

  const int sR = lane >> 3;
  const int sC = (lane & 7) ^ sR;
  const bf16* gA = A + (size_t)(m0 + sR) * lda + sC * 8;
  const bf16* gB = B + (size_t)(n0 + sR) * ldb + sC * 8;

  f32x4 acc[2][2];
#pragma unroll
  for (int i = 0; i < 2; ++i)
#pragma unroll
    for (int j = 0; j < 2; ++j)
      acc[i][j] = (f32x4){0.f, 0.f, 0.f, 0.f};

  const int wr = wave >> 1, wc = wave & 1;
  const int mW = wr * 32, nW = wc * 32;
  const int fragRow = lane & 15;
  const int quad = lane >> 4;

  auto stage = [&](int kt, int buf) {
    bf16* dA = As + buf * (64 * 64);
    bf16* dB = Bs + buf * (64 * 64);
#pragma unroll
    for (int t = 0; t < 2; ++t) {
      const int R = (t * 4 + wave) * 8;
      GLOAD_LDS16(gA + (size_t)R * lda + kt, &dA[R * 64]);
      GLOAD_LDS16(gB + (size_t)R * ldb + kt, &dB[R * 64]);
    }
  };

  const int nT = K >> 6;               // 16
  stage(0, 0);
  stage(64, 1);
  int bufC = 0;
  for (int kt = 0; kt < nT; ++kt) {
    if (kt + 2 < nT) {
      int bs = bufC + 2; if (bs >= 3) bs -= 3;
      stage((kt + 2) << 6, bs);
      asm volatile("s_waitcnt vmcnt(8)" ::: "memory");   // tile kt done (4 loads/stage)
    } else if (kt + 1 < nT) {
      asm volatile("s_waitcnt vmcnt(4)" ::: "memory");
    } else {
      asm volatile("s_waitcnt vmcnt(0)" ::: "memory");
    }
    asm volatile("s_barrier" ::: "memory");

    const bf16* Ab = As + bufC * (64 * 64);
    const bf16* Bb = Bs + bufC * (64 * 64);
    bf16x8 afr[2][2], bfr[2][2];
#pragma unroll
    for (int s = 0; s < 2; ++s) {
      const int cw = s * 4 + quad;
#pragma unroll
      for (int i = 0; i < 2; ++i) {
        const int ra = mW + i * 16 + fragRow;
        afr[s][i] = *(const bf16x8*)&Ab[ra * 64 + ((cw ^ (ra & 7)) << 3)];
        const int rb = nW + i * 16 + fragRow;
        bfr[s][i] = *(const bf16x8*)&Bb[rb * 64 + ((cw ^ (rb & 7)) << 3)];
      }
    }
    asm volatile("s_waitcnt lgkmcnt(0)" ::: "memory");
    asm volatile("s_barrier" ::: "memory");

#pragma unroll
    for (int s = 0; s < 2; ++s)
#pragma unroll
      for (int i = 0; i < 2; ++i)
#pragma unroll
        for (int j = 0; j < 2; ++j)
          acc[i][j] = __builtin_amdgcn_mfma_f32_16x16x32_bf16(afr[s][i], bfr[s][j], acc[i][j], 0, 0, 0);

    bufC = (bufC == 2) ? 0 : bufC + 1;
  }

  const int cCol  = lane & 15;
  const int cRow4 = quad * 4;
#pragma unroll
  for (int i = 0; i < 2; ++i)
#pragma unroll
    for (int j = 0; j < 2; ++j) {
      const int row = m0 + mW + i * 16 + cRow4;
      const int col = n0 + nW + j * 16 + cCol;
#pragma unroll
      for (int r = 0; r < 4; ++r)
        store_out(&C[(size_t)(row + r) * ldc + col], acc[i][j][r]);
    }
}

// ---------------------------------------------------------------------------
// THE mega-kernel: entire pipeline in one dispatch, 512 blocks x 256 threads.
// Phases separated by device-scope grid barriers (counters zeroed via memset).
__global__ __launch_bounds__(256, 2) void mega(
    const float* __restrict__ x, const float* __restrict__ WQ,
    const float* __restrict__ WK, const float* __restrict__ WV,
    float* __restrict__ out,
    bf16* __restrict__ xb, bf16* __restrict__ xTb,
    bf16* __restrict__ WQb, bf16* __restrict__ WKb, bf16* __restrict__ WVTb,
    bf16* __restrict__ Gb, bf16* __restrict__ P1b, bf16* __restrict__ Utb,
    bf16* __restrict__ WpTb, bf16* __restrict__ part, unsigned* __restrict__ ctr)
{
  __shared__ bf16 sm[4 * 128 * 64];   // 64 KB, reused across phases
  const int b = blockIdx.x;
  const int tid = threadIdx.x;

  // ---------------- phase 0: prep (casts + transposes) ----------------
  {
    // transposes: 1024 tiles (x->xTb) + 128 tiles (WV->WVTb), 128x64 each
    bf16 (*t)[68] = (bf16(*)[68])sm;
    for (int tt = b; tt < 1152; tt += NB) {
      const float* src; bf16* dst; int ldOut, tr, tc;
      if (tt < 1024) { src = x;  dst = xTb;  ldOut = SEQ; tr = tt >> 4; tc = tt & 15; }
      else { int u = tt - 1024; src = WV; dst = WVTb; ldOut = DIN; tr = u >> 4; tc = u & 15; }
      const int r0 = tr * 128, c0 = tc * 64;
      __syncthreads();   // protect LDS reuse from previous tile
#pragma unroll
      for (int p = 0; p < 8; ++p) {
        const int q = tid + p * 256;
        const int r = q >> 4, c4 = (q & 15) * 4;
        const float4 f = *(const float4*)&src[(size_t)(r0 + r) * DIN + c0 + c4];
        short4 s4;
        s4.x = bfbits(f.x); s4.y = bfbits(f.y); s4.z = bfbits(f.z); s4.w = bfbits(f.w);
        *(short4*)&t[r][c4] = s4;
      }
      __syncthreads();
#pragma unroll
      for (int p = 0; p < 4; ++p) {
        const int h = tid + p * 256;
        const int c = h >> 4, seg = h & 15;
        bf16x8 o;
#pragma unroll
        for (int i = 0; i < 8; ++i)
          o[i] = *(const short*)&t[seg * 8 + i][c];
        *(bf16x8*)&dst[(size_t)(c0 + c) * ldOut + r0 + seg * 8] = o;
      }
    }
    // flat casts: x->xb (8.4M), WQ->WQb (1M), WK->WKb (1M); bf16x8 per thread
    for (int q = b * 256 + tid; q < 1310720; q += NB * 256) {
      const size_t i = (size_t)q * 8;
      const float* src; bf16* dst;
      if (i < 8388608)      { src = x  + i;             dst = xb  + i; }
      else if (i < 9437184) { src = WQ + (i - 8388608); dst = WQb + (i - 8388608); }
      else                  { src = WK + (i - 9437184); dst = WKb + (i - 9437184); }
      const float4 f0 = *(const float4*)src;
      const float4 f1 = *(const float4*)(src + 4);
      bf16x8 o;
      o[0] = bfbits(f0.x); o[1] = bfbits(f0.y); o[2] = bfbits(f0.z); o[3] = bfbits(f0.w);
      o[4] = bfbits(f1.x); o[5] = bfbits(f1.y); o[6] = bfbits(f1.z); o[7] = bfbits(f1.w);
      *(bf16x8*)dst = o;
    }
  }
  grid_barrier(&ctr[0], NB);

  // ---------------- phase A: G split-K partials (all 512 blocks) --------
  {
    const int z = b & 7;       // XCD-local K-chunk (2 MB slice L2-resident)
    const int r = b >> 3;
    const bf16* Az = xTb + (size_t)z * 1024;
    gemm128_body<bf16>(Az, Az, part + ((size_t)z << 20),
                       r & 7, r >> 3, 1024, 8192, 8192, 1024,
                       sm, sm + 2 * 128 * 64);
  }
  grid_barrier(&ctr[1], NB);

  // ---------------- phase B: P1 = WQ WK^T (0-255)  ||  reduce G (256-511)
  if (b < 256) {
    gemm64_body<bf16>(WQb, WKb, P1b, b & 15, b >> 4, 1024, 1024, 1024, 1024,
                      sm, sm + 3 * 64 * 64);
  } else {
    const int h = (b - 256) * 256 + tid;       // 0..65535, 16 elems each
    const size_t base = (size_t)h * 16;
    float s[16];
#pragma unroll
    for (int r = 0; r < 16; ++r) s[r] = 0.f;
    for (int z = 0; z < 8; ++z) {
      const bf16x8 v0 = *(const bf16x8*)&part[((size_t)z << 20) + base];
      const bf16x8 v1 = *(const bf16x8*)&part[((size_t)z << 20) + base + 8];
#pragma unroll
      for (int r = 0; r < 8; ++r) { s[r] += bf2f(v0[r]); s[8 + r] += bf2f(v1[r]); }
    }
    bf16x8 o0, o1;
#pragma unroll
    for (int r = 0; r < 8; ++r) { o0[r] = bfbits(s[r]); o1[r] = bfbits(s[8 + r]); }
    *(bf16x8*)&Gb[base] = o0;
    *(bf16x8*)&Gb[base + 8] = o1;
  }
  grid_barrier(&ctr[2], NB);

  // ---------------- phase C: Ut = WV^T G (G symmetric -> B^T = G) -------
  if (b < 256)
    gemm64_body<bf16>(WVTb, Gb, Utb, b & 15, b >> 4, 1024, 1024, 1024, 1024,
                      sm, sm + 3 * 64 * 64);
  grid_barrier(&ctr[3], NB);

  // ---------------- phase D: W'^T = Ut P1^T -----------------------------
  if (b < 256)
    gemm64_body<bf16>(Utb, P1b, WpTb, b & 15, b >> 4, 1024, 1024, 1024, 1024,
                      sm, sm + 3 * 64 * 64);
  grid_barrier(&ctr[4], NB);

  // ---------------- phase E: out = x W'  (XCD-swizzled) -----------------
  {
    const int by = ((b & 7) << 3) | ((b >> 3) & 7);
    const int bx = b >> 6;
    gemm128_body<float>(xb, WpTb, out, bx, by, 1024, 1024, 1024, DOUT,
                        sm, sm + 2 * 128 * 64);
  }
}

// ---------------------------------------------------------------------------
extern "C" void kernel_launch(void* const* d_in, const int* in_sizes, int n_in,
                              void* d_out, int out_size, void* d_ws, size_t ws_size,
                              hipStream_t stream)
{
  const float* x  = (const float*)d_in[0];
  const float* WQ = (const float*)d_in[1];
  const float* WK = (const float*)d_in[2];
  const float* WV = (const float*)d_in[3];
  float* out = (float*)d_out;

  char* ws = (char*)d_ws;
  size_t off = 0;
  auto alloc = [&](size_t bytes) -> void* {
    void* p = ws + off;
    off += (bytes + 255) & ~(size_t)255;
    return p;
  };

  const size_t xBytes = (size_t)SEQ * DIN * sizeof(bf16);
  const size_t wBytes = (size_t)DIN * DOUT * sizeof(bf16);

  unsigned* ctr = (unsigned*)alloc(8 * sizeof(unsigned));  // barrier counters
  bf16* xb   = (bf16*)alloc(xBytes);
  bf16* xTb  = (bf16*)alloc(xBytes);
  bf16* WQb  = (bf16*)alloc(wBytes);
  bf16* WKb  = (bf16*)alloc(wBytes);
  bf16* WVTb = (bf16*)alloc(wBytes);
  bf16* Gb   = (bf16*)alloc(wBytes);
  bf16* P1b  = (bf16*)alloc(wBytes);
  bf16* Utb  = (bf16*)alloc(wBytes);
  bf16* WpTb = (bf16*)alloc(wBytes);
  bf16* part = (bf16*)alloc(8 * wBytes);   // split-K partials

  hipMemsetAsync(ctr, 0, 8 * sizeof(unsigned), stream);  // capture-safe
  mega<<<dim3(NB), 256, 0, stream>>>(x, WQ, WK, WV, out,
                                     xb, xTb, WQb, WKb, WVTb,
                                     Gb, P1b, Utb, WpTb, part, ctr);
}

// Round 7
// 165.395 us; speedup vs baseline: 2.5412x; 2.5412x over previous
//
#include <hip/hip_runtime.h>
#include <hip/hip_bf16.h>
#include <stdint.h>
#include <stddef.h>

#define SEQ  8192
#define DIN  1024
#define DOUT 1024

typedef __hip_bfloat16 bf16;
typedef short bf16x8 __attribute__((ext_vector_type(8)));   // 8 bf16 = 4 VGPRs
typedef float f32x4  __attribute__((ext_vector_type(4)));

// async global->LDS, 16B per lane; dest = wave-uniform base + lane*16
#define GLOAD_LDS16(gptr, lptr)                                                     \
  __builtin_amdgcn_global_load_lds(                                                 \
      (const __attribute__((address_space(1))) void*)(gptr),                        \
      (__attribute__((address_space(3))) void*)(lptr), 16, 0, 0)

__device__ inline void store_out(float* p, float v) { *p = v; }
__device__ inline void store_out(bf16* p, float v) { *p = __float2bfloat16(v); }
__device__ inline short bfbits(float f) { bf16 b = __float2bfloat16(f); return *(short*)&b; }
__device__ inline float bf2f(short u) {
  unsigned v = ((unsigned)(unsigned short)u) << 16;
  return __uint_as_float(v);
}

// ---------------------------------------------------------------------------
// 128x128 tile, BK=32, 4 LDS buffers, 3-deep prefetch (steady-state vmcnt(12),
// never drains). Buffer = 128 rows x 32 cols bf16 = 8 KB; As/Bs 32 KB each.
// Swizzle: element (row r, chunk c[0..3]) stored at slot chunk c ^ ((r>>1)&3)
// -> ds_read_b128 quads hit 8 distinct bank groups (2-way = free).
// Requires K >= 96 (nT >= 3).
template <typename OutT>
__device__ __forceinline__ void gemm128_body(
    const bf16* __restrict__ A, const bf16* __restrict__ B, OutT* __restrict__ C,
    int bx, int by, int K, int lda, int ldb, int ldc, bf16* As, bf16* Bs)
{
  const int lane = threadIdx.x & 63;
  const int wave = threadIdx.x >> 6;
  const int m0 = by * 128, n0 = bx * 128;

  // staging: one call = one 16-row group (64 lanes x 16B = 16 rows x 64B).
  // lane l -> row l>>2, slot chunk l&3, so fetch global chunk (l&3)^((l>>3)&3).
  const int sR = lane >> 2;
  const int sC = (lane & 3) ^ ((lane >> 3) & 3);
  const bf16* gA = A + (size_t)(m0 + sR) * lda + sC * 8;
  const bf16* gB = B + (size_t)(n0 + sR) * ldb + sC * 8;

  f32x4 acc[4][4];
#pragma unroll
  for (int i = 0; i < 4; ++i)
#pragma unroll
    for (int j = 0; j < 4; ++j)
      acc[i][j] = (f32x4){0.f, 0.f, 0.f, 0.f};

  const int wr = wave >> 1, wc = wave & 1;
  const int mW = wr * 64, nW = wc * 64;
  const int fragRow = lane & 15;
  const int q = lane >> 4;              // k-offset quad (k0 = q*8)

  auto stage = [&](int kt, int buf) {   // 4 loads/wave -> vmcnt +4 per stage
    bf16* dA = As + buf * (128 * 32);
    bf16* dB = Bs + buf * (128 * 32);
#pragma unroll
    for (int t = 0; t < 2; ++t) {
      const int g = t * 4 + wave;       // 16-row group 0..7
      GLOAD_LDS16(gA + (size_t)g * 16 * lda + kt, &dA[g * 16 * 32]);
      GLOAD_LDS16(gB + (size_t)g * 16 * ldb + kt, &dB[g * 16 * 32]);
    }
  };

  const int nT = K >> 5;
  stage(0, 0); stage(32, 1); stage(64, 2);
  for (int kt = 0; kt < nT; ++kt) {
    const int buf = kt & 3;
    if (kt + 3 < nT) {
      stage((kt + 3) << 5, (kt + 3) & 3);
      asm volatile("s_waitcnt vmcnt(12)" ::: "memory");  // stage kt complete
    } else if (kt + 2 < nT) {
      asm volatile("s_waitcnt vmcnt(8)" ::: "memory");
    } else if (kt + 1 < nT) {
      asm volatile("s_waitcnt vmcnt(4)" ::: "memory");
    } else {
      asm volatile("s_waitcnt vmcnt(0)" ::: "memory");
    }
    asm volatile("s_barrier" ::: "memory");

    const bf16* Ab = As + buf * (128 * 32);
    const bf16* Bb = Bs + buf * (128 * 32);
    bf16x8 afr[4], bfr[4];
#pragma unroll
    for (int i = 0; i < 4; ++i) {
      const int ra = mW + i * 16 + fragRow;
      afr[i] = *(const bf16x8*)&Ab[ra * 32 + ((q ^ ((ra >> 1) & 3)) << 3)];
      const int rb = nW + i * 16 + fragRow;
      bfr[i] = *(const bf16x8*)&Bb[rb * 32 + ((q ^ ((rb >> 1) & 3)) << 3)];
    }
    asm volatile("s_waitcnt lgkmcnt(0)" ::: "memory");
    asm volatile("s_barrier" ::: "memory");   // buf (kt-1)&3 now safe to refill

#pragma unroll
    for (int i = 0; i < 4; ++i)
#pragma unroll
      for (int j = 0; j < 4; ++j)
        acc[i][j] = __builtin_amdgcn_mfma_f32_16x16x32_bf16(afr[i], bfr[j], acc[i][j], 0, 0, 0);
  }

  const int cCol  = lane & 15;
  const int cRow4 = q * 4;
#pragma unroll
  for (int i = 0; i < 4; ++i)
#pragma unroll
    for (int j = 0; j < 4; ++j) {
      const int row = m0 + mW + i * 16 + cRow4;
      const int col = n0 + nW + j * 16 + cCol;
#pragma unroll
      for (int r = 0; r < 4; ++r)
        store_out(&C[(size_t)(row + r) * ldc + col], acc[i][j][r]);
    }
}

// 64x64 tile, BK=64, XOR swizzle, triple-buffered. As/Bs: 3 x 64*64 bf16.
template <typename OutT>
__device__ __forceinline__ void gemm64_body(
    const bf16* __restrict__ A, const bf16* __restrict__ B, OutT* __restrict__ C,
    int bx, int by, int K, int lda, int ldb, int ldc, bf16* As, bf16* Bs)
{
  const int lane = threadIdx.x & 63;
  const int wave = threadIdx.x >> 6;
  const int m0 = by * 64, n0 = bx * 64;

  const int sR = lane >> 3;
  const int sC = (lane & 7) ^ sR;
  const bf16* gA = A + (size_t)(m0 + sR) * lda + sC * 8;
  const bf16* gB = B + (size_t)(n0 + sR) * ldb + sC * 8;

  f32x4 acc[2][2];
#pragma unroll
  for (int i = 0; i < 2; ++i)
#pragma unroll
    for (int j = 0; j < 2; ++j)
      acc[i][j] = (f32x4){0.f, 0.f, 0.f, 0.f};

  const int wr = wave >> 1, wc = wave & 1;
  const int mW = wr * 32, nW = wc * 32;
  const int fragRow = lane & 15;
  const int quad = lane >> 4;

  auto stage = [&](int kt, int buf) {
    bf16* dA = As + buf * (64 * 64);
    bf16* dB = Bs + buf * (64 * 64);
#pragma unroll
    for (int t = 0; t < 2; ++t) {
      const int R = (t * 4 + wave) * 8;
      GLOAD_LDS16(gA + (size_t)R * lda + kt, &dA[R * 64]);
      GLOAD_LDS16(gB + (size_t)R * ldb + kt, &dB[R * 64]);
    }
  };

  const int nT = K >> 6;               // 16
  stage(0, 0);
  stage(64, 1);
  int bufC = 0;
  for (int kt = 0; kt < nT; ++kt) {
    if (kt + 2 < nT) {
      int bs = bufC + 2; if (bs >= 3) bs -= 3;
      stage((kt + 2) << 6, bs);
      asm volatile("s_waitcnt vmcnt(8)" ::: "memory");
    } else if (kt + 1 < nT) {
      asm volatile("s_waitcnt vmcnt(4)" ::: "memory");
    } else {
      asm volatile("s_waitcnt vmcnt(0)" ::: "memory");
    }
    asm volatile("s_barrier" ::: "memory");

    const bf16* Ab = As + bufC * (64 * 64);
    const bf16* Bb = Bs + bufC * (64 * 64);
    bf16x8 afr[2][2], bfr[2][2];
#pragma unroll
    for (int s = 0; s < 2; ++s) {
      const int cw = s * 4 + quad;
#pragma unroll
      for (int i = 0; i < 2; ++i) {
        const int ra = mW + i * 16 + fragRow;
        afr[s][i] = *(const bf16x8*)&Ab[ra * 64 + ((cw ^ (ra & 7)) << 3)];
        const int rb = nW + i * 16 + fragRow;
        bfr[s][i] = *(const bf16x8*)&Bb[rb * 64 + ((cw ^ (rb & 7)) << 3)];
      }
    }
    asm volatile("s_waitcnt lgkmcnt(0)" ::: "memory");
    asm volatile("s_barrier" ::: "memory");

#pragma unroll
    for (int s = 0; s < 2; ++s)
#pragma unroll
      for (int i = 0; i < 2; ++i)
#pragma unroll
        for (int j = 0; j < 2; ++j)
          acc[i][j] = __builtin_amdgcn_mfma_f32_16x16x32_bf16(afr[s][i], bfr[s][j], acc[i][j], 0, 0, 0);

    bufC = (bufC == 2) ? 0 : bufC + 1;
  }

  const int cCol  = lane & 15;
  const int cRow4 = quad * 4;
#pragma unroll
  for (int i = 0; i < 2; ++i)
#pragma unroll
    for (int j = 0; j < 2; ++j) {
      const int row = m0 + mW + i * 16 + cRow4;
      const int col = n0 + nW + j * 16 + cCol;
#pragma unroll
      for (int r = 0; r < 4; ++r)
        store_out(&C[(size_t)(row + r) * ldc + col], acc[i][j][r]);
    }
}

// ---------------------------------------------------------------------------
// merged: blocks 0..287 = G split-K partials, UPPER TRIANGLE only (36 tiles x
// 8 K-chunks, z = b&7 XCD-local); blocks 288..543 = P1 = WQ WK^T.
__global__ __launch_bounds__(256) void g_p1(
    const bf16* __restrict__ xT, const bf16* __restrict__ WQb,
    const bf16* __restrict__ WKb, bf16* __restrict__ part, bf16* __restrict__ P1)
{
  __shared__ bf16 sm[32768];  // 64 KB
  const int b = blockIdx.x;
  if (b < 288) {
    const int z = b & 7;
    int u = b >> 3;                      // 0..35 upper-tile id
    int ti = 0;
    while (u >= 8 - ti) { u -= 8 - ti; ++ti; }
    const int tj = ti + u;               // ti <= tj
    const bf16* Az = xT + (size_t)z * 1024;
    gemm128_body<bf16>(Az, Az, part + ((size_t)z << 20),
                       tj, ti, 1024, 8192, 8192, 1024,
                       sm, sm + 4 * 128 * 32);
  } else {
    const int p = b - 288;
    gemm64_body<bf16>(WQb, WKb, P1, p & 15, p >> 4, 1024, 1024, 1024, 1024,
                      sm, sm + 3 * 64 * 64);
  }
}

// final GEMM: XCD-swizzled (each XCD's blocks share A row-slices).
__global__ __launch_bounds__(256) void gemm128_f32(
    const bf16* __restrict__ A, const bf16* __restrict__ B, float* __restrict__ C,
    int K, int lda, int ldb, int ldc)
{
  __shared__ bf16 sm[32768];
  const int id = blockIdx.x;
  const int by = ((id & 7) << 3) | ((id >> 3) & 7);
  const int bx = id >> 6;
  gemm128_body<float>(A, B, C, bx, by, K, lda, ldb, ldc, sm, sm + 4 * 128 * 32);
}

__global__ __launch_bounds__(256) void gemm64_bf(
    const bf16* __restrict__ A, const bf16* __restrict__ B, bf16* __restrict__ C,
    int K, int lda, int ldb, int ldc)
{
  __shared__ bf16 sm[6 * 64 * 64];
  gemm64_body<bf16>(A, B, C, blockIdx.x, blockIdx.y, K, lda, ldb, ldc,
                    sm, sm + 3 * 64 * 64);
}

// ---------------------------------------------------------------------------
// prep_all: all casts/transposes, one dispatch.
__global__ __launch_bounds__(256) void prep_all(
    const float* __restrict__ x, const float* __restrict__ WQ,
    const float* __restrict__ WK, const float* __restrict__ WV,
    bf16* __restrict__ xb, bf16* __restrict__ xTb,
    bf16* __restrict__ WQb, bf16* __restrict__ WKb, bf16* __restrict__ WVTb)
{
  __shared__ bf16 t[128][68];
  int b = blockIdx.x;

  if (b < 5120) {
    const size_t i = ((size_t)b * 256 + threadIdx.x) * 8;
    const float* src; bf16* dst;
    if (i < 8388608)      { src = x  + i;             dst = xb  + i; }
    else if (i < 9437184) { src = WQ + (i - 8388608); dst = WQb + (i - 8388608); }
    else                  { src = WK + (i - 9437184); dst = WKb + (i - 9437184); }
    const float4 f0 = *(const float4*)src;
    const float4 f1 = *(const float4*)(src + 4);
    bf16x8 o;
    o[0] = bfbits(f0.x); o[1] = bfbits(f0.y); o[2] = bfbits(f0.z); o[3] = bfbits(f0.w);
    o[4] = bfbits(f1.x); o[5] = bfbits(f1.y); o[6] = bfbits(f1.z); o[7] = bfbits(f1.w);
    *(bf16x8*)dst = o;
    return;
  }

  b -= 5120;
  const float* src; bf16* dst; int ldOut, tr, tc;
  if (b < 1024) { src = x;  dst = xTb;  ldOut = SEQ; tr = b >> 4; tc = b & 15; }
  else { b -= 1024; src = WV; dst = WVTb; ldOut = DIN; tr = b >> 4; tc = b & 15; }
  const int r0 = tr * 128, c0 = tc * 64;

#pragma unroll
  for (int p = 0; p < 8; ++p) {
    const int q = threadIdx.x + p * 256;
    const int r = q >> 4, c4 = (q & 15) * 4;
    const float4 f = *(const float4*)&src[(size_t)(r0 + r) * DIN + c0 + c4];
    short4 s4;
    s4.x = bfbits(f.x); s4.y = bfbits(f.y); s4.z = bfbits(f.z); s4.w = bfbits(f.w);
    *(short4*)&t[r][c4] = s4;
  }
  __syncthreads();

#pragma unroll
  for (int p = 0; p < 4; ++p) {
    const int h = threadIdx.x + p * 256;
    const int c = h >> 4, seg = h & 15;
    bf16x8 o;
#pragma unroll
    for (int i = 0; i < 8; ++i)
      o[i] = *(const short*)&t[seg * 8 + i][c];
    *(bf16x8*)&dst[(size_t)(c0 + c) * ldOut + r0 + seg * 8] = o;
  }
}

// ---------------------------------------------------------------------------
// reduceT: one block per upper tile (36 blocks). Sums 8 partials of tile
// (ti,tj), writes G[ti,tj], and mirrors to G[tj,ti] via transposed LDS stash.
// (i,j)/(j,i) dot products round identically -> exact symmetry, safe.
__global__ __launch_bounds__(256) void reduceT(const bf16* __restrict__ part,
                                               bf16* __restrict__ Gb)
{
  __shared__ bf16 t[128][129];           // t[col][row] (transposed stash)
  int u = blockIdx.x, ti = 0;
  while (u >= 8 - ti) { u -= 8 - ti; ++ti; }
  const int tj = ti + u;
  const int r0 = ti * 128, c0 = tj * 128;
  const int tid = threadIdx.x;

#pragma unroll
  for (int p = 0; p < 8; ++p) {
    const int idx = tid + p * 256;       // 2048 chunks of 8 elems
    const int r = idx >> 4, c8 = (idx & 15) * 8;
    float s[8] = {0.f, 0.f, 0.f, 0.f, 0.f, 0.f, 0.f, 0.f};
    for (int z = 0; z < 8; ++z) {
      bf16x8 v = *(const bf16x8*)&part[((size_t)z << 20) + (size_t)(r0 + r) * 1024 + c0 + c8];
#pragma unroll
      for (int e = 0; e < 8; ++e) s[e] += bf2f(v[e]);
    }
    bf16x8 o;
#pragma unroll
    for (int e = 0; e < 8; ++e) o[e] = bfbits(s[e]);
    *(bf16x8*)&Gb[(size_t)(r0 + r) * 1024 + c0 + c8] = o;
#pragma unroll
    for (int e = 0; e < 8; ++e) {
      const short se = o[e];                       // addressable copy
      t[c8 + e][r] = *(const bf16*)&se;
    }
  }
  if (ti == tj) return;
  __syncthreads();

  // mirrored tile (tj,ti): element (rr,cc) = t[rr][cc] (row-major in t)
#pragma unroll
  for (int p = 0; p < 8; ++p) {
    const int idx = tid + p * 256;
    const int rr = idx >> 4, c8 = (idx & 15) * 8;
    bf16x8 o;
#pragma unroll
    for (int e = 0; e < 8; ++e)
      o[e] = *(const short*)&t[rr][c8 + e];
    *(bf16x8*)&Gb[(size_t)(c0 + rr) * 1024 + r0 + c8] = o;
  }
}

// ---------------------------------------------------------------------------
extern "C" void kernel_launch(void* const* d_in, const int* in_sizes, int n_in,
                              void* d_out, int out_size, void* d_ws, size_t ws_size,
                              hipStream_t stream)
{
  const float* x  = (const float*)d_in[0];
  const float* WQ = (const float*)d_in[1];
  const float* WK = (const float*)d_in[2];
  const float* WV = (const float*)d_in[3];
  float* out = (float*)d_out;

  char* ws = (char*)d_ws;
  size_t off = 0;
  auto alloc = [&](size_t bytes) -> void* {
    void* p = ws + off;
    off += (bytes + 255) & ~(size_t)255;
    return p;
  };

  const size_t xBytes = (size_t)SEQ * DIN * sizeof(bf16);
  const size_t wBytes = (size_t)DIN * DOUT * sizeof(bf16);
  const int S = 8;

  bf16* xb   = (bf16*)alloc(xBytes);   // x, bf16
  bf16* xTb  = (bf16*)alloc(xBytes);   // x^T, bf16
  bf16* WQb  = (bf16*)alloc(wBytes);
  bf16* WKb  = (bf16*)alloc(wBytes);
  bf16* WVTb = (bf16*)alloc(wBytes);   // WV^T
  bf16* Gb   = (bf16*)alloc(wBytes);   // x^T x (symmetric)
  bf16* P1b  = (bf16*)alloc(wBytes);   // WQ WK^T
  bf16* Utb  = (bf16*)alloc(wBytes);   // WV^T G
  bf16* WpTb = (bf16*)alloc(wBytes);   // W'^T = Ut P1^T
  bf16* part = (bf16*)alloc((size_t)S * wBytes);  // split-K partials

  // 1. casts + transposes
  prep_all<<<dim3(6272), 256, 0, stream>>>(x, WQ, WK, WV, xb, xTb, WQb, WKb, WVTb);

  // 2. G upper-triangle split-K partials (288) || P1 = WQ WK^T (256)
  g_p1<<<dim3(544), 256, 0, stream>>>(xTb, WQb, WKb, part, P1b);

  // 3. G = sum partials, + mirror lower triangle
  reduceT<<<dim3(36), 256, 0, stream>>>(part, Gb);

  // 4. Ut = WV^T G  (G symmetric -> B^T = G)
  gemm64_bf<<<dim3(16, 16), 256, 0, stream>>>(WVTb, Gb, Utb, 1024, 1024, 1024, 1024);
  // 5. W'^T = Ut P1^T
  gemm64_bf<<<dim3(16, 16), 256, 0, stream>>>(Utb, P1b, WpTb, 1024, 1024, 1024, 1024);

  // 6. out = x W'  (XCD-swizzled)
  gemm128_f32<<<dim3(512), 256, 0, stream>>>(xb, WpTb, out, 1024, 1024, 1024, DOUT);
}